// Round 1
// baseline (435.033 us; speedup 1.0000x reference)
//
#include <hip/hip_runtime.h>

// x layout: [B=8, Tt=128, Ts=128, C=512] fp32, row-major.
// cummax along Ts (axis 2). For each (b,t,c): out[s] = max(x[0..s]).
// One thread per (row = b*Tt+t, c-quad). 128 threads cover one row's C=512
// as float4; thread walks s=0..127 with running max in registers.
// Fully coalesced 16B/lane loads and stores.

__global__ __launch_bounds__(256) void cummax_ts_kernel(
    const float4* __restrict__ x, float4* __restrict__ out) {
    constexpr int TS = 128;
    constexpr int CV = 128;  // C/4 = 512/4

    const int gid = blockIdx.x * blockDim.x + threadIdx.x;
    const int row = gid >> 7;      // / CV
    const int cv  = gid & (CV - 1);

    const size_t base = (size_t)row * TS * CV + cv;
    const float4* __restrict__ p = x + base;
    float4* __restrict__ q = out + base;

    float4 m = p[0];
    q[0] = m;
#pragma unroll 4
    for (int s = 1; s < TS; ++s) {
        float4 v = p[(size_t)s * CV];
        m.x = fmaxf(m.x, v.x);
        m.y = fmaxf(m.y, v.y);
        m.z = fmaxf(m.z, v.z);
        m.w = fmaxf(m.w, v.w);
        q[(size_t)s * CV] = m;
    }
}

extern "C" void kernel_launch(void* const* d_in, const int* in_sizes, int n_in,
                              void* d_out, int out_size, void* d_ws, size_t ws_size,
                              hipStream_t stream) {
    const float4* x = (const float4*)d_in[0];
    float4* out = (float4*)d_out;

    // B*Tt = 1024 rows, CV = 128 quads per row -> 131072 threads.
    constexpr int ROWS = 8 * 128;
    constexpr int CV = 128;
    constexpr int BLOCK = 256;
    const int total = ROWS * CV;
    cummax_ts_kernel<<<total / BLOCK, BLOCK, 0, stream>>>(x, out);
}

// Round 2
// 430.910 us; speedup vs baseline: 1.0096x; 1.0096x over previous
//
#include <hip/hip_runtime.h>

// x: [B=8, Tt=128, Ts=128, C=512] fp32 row-major; cummax along Ts.
// Chunked scan: block = 256 threads = 4 s-chunks (wave-uniform) x 64 c-quads,
// covering one (row, half-C). Each thread:
//   1) loads its 32-step chunk into registers (32 independent float4 loads
//      in flight -> MLP covers HBM latency),
//   2) in-register prefix max,
//   3) exchanges chunk totals via LDS, computes carry (prefix of totals),
//   4) stores max(carry, v[i]) -- 32 coalesced float4 stores.
// All loads/stores are 16 B/lane, 64 consecutive lanes -> 1 KiB/instr.

constexpr int TS = 128;
constexpr int CV = 128;            // C/4
constexpr int CHUNK = 32;          // s-steps per thread
constexpr int NCHUNK = TS / CHUNK; // 4
constexpr int CVB = 64;            // c-quads per block

__global__ __launch_bounds__(256, 3) void cummax_scan(
    const float4* __restrict__ x, float4* __restrict__ out) {
  __shared__ float4 totals[NCHUNK][CVB];  // 4 KiB

  const int tid   = threadIdx.x;
  const int chunk = tid >> 6;   // wave index == chunk index (wave-uniform)
  const int cvl   = tid & 63;
  const int row   = blockIdx.x >> 1;
  const int cv    = ((blockIdx.x & 1) << 6) | cvl;

  const size_t base = ((size_t)row * TS + (size_t)chunk * CHUNK) * CV + cv;
  const float4* __restrict__ p = x + base;
  float4*       __restrict__ q = out + base;

  // 1) batch-load chunk into registers (all independent)
  float4 v[CHUNK];
#pragma unroll
  for (int i = 0; i < CHUNK; ++i) v[i] = p[(size_t)i * CV];

  // 2) in-register prefix max (4 independent chains of 31)
#pragma unroll
  for (int i = 1; i < CHUNK; ++i) {
    v[i].x = fmaxf(v[i].x, v[i - 1].x);
    v[i].y = fmaxf(v[i].y, v[i - 1].y);
    v[i].z = fmaxf(v[i].z, v[i - 1].z);
    v[i].w = fmaxf(v[i].w, v[i - 1].w);
  }

  // 3) chunk totals -> LDS -> carry
  totals[chunk][cvl] = v[CHUNK - 1];
  __syncthreads();

  const float ninf = -__builtin_inff();
  float4 carry = make_float4(ninf, ninf, ninf, ninf);
  for (int c = 0; c < chunk; ++c) {  // wave-uniform trip count
    float4 t = totals[c][cvl];
    carry.x = fmaxf(carry.x, t.x);
    carry.y = fmaxf(carry.y, t.y);
    carry.z = fmaxf(carry.z, t.z);
    carry.w = fmaxf(carry.w, t.w);
  }

  // 4) apply carry + store
#pragma unroll
  for (int i = 0; i < CHUNK; ++i) {
    float4 o;
    o.x = fmaxf(carry.x, v[i].x);
    o.y = fmaxf(carry.y, v[i].y);
    o.z = fmaxf(carry.z, v[i].z);
    o.w = fmaxf(carry.w, v[i].w);
    q[(size_t)i * CV] = o;
  }
}

extern "C" void kernel_launch(void* const* d_in, const int* in_sizes, int n_in,
                              void* d_out, int out_size, void* d_ws, size_t ws_size,
                              hipStream_t stream) {
  const float4* x = (const float4*)d_in[0];
  float4* out = (float4*)d_out;

  // 1024 rows x 2 half-C blocks = 2048 blocks of 256 threads.
  constexpr int ROWS = 8 * 128;
  cummax_scan<<<ROWS * 2, 256, 0, stream>>>(x, out);
}

// Round 3
// 427.424 us; speedup vs baseline: 1.0178x; 1.0082x over previous
//
#include <hip/hip_runtime.h>

// x: [B=8, Tt=128, Ts=128, C=512] fp32 row-major; cummax along Ts (axis 2).
// Chunked scan, spill-free variant: block = 512 threads = 8 s-chunks
// (wave-uniform, chunk == wave id) x 64 c-quads, covering (row, half-C).
// Per thread: 16 independent float4 loads -> in-register prefix max ->
// chunk totals through LDS -> carry -> 16 coalesced float4 stores.
// v[16] float4 = 64 VGPRs for data; no launch-bounds clamp -> no spill.

constexpr int TS = 128;
constexpr int CV = 128;            // C/4
constexpr int CHUNK = 16;          // s-steps per thread
constexpr int NCHUNK = TS / CHUNK; // 8
constexpr int CVB = 64;            // c-quads per block

__global__ __launch_bounds__(512) void cummax_scan(
    const float4* __restrict__ x, float4* __restrict__ out) {
  __shared__ float4 totals[NCHUNK][CVB];  // 8 KiB

  const int tid   = threadIdx.x;
  const int chunk = tid >> 6;   // wave index == chunk index (wave-uniform)
  const int cvl   = tid & 63;
  const int row   = blockIdx.x >> 1;
  const int cv    = ((blockIdx.x & 1) << 6) | cvl;

  const size_t base = ((size_t)row * TS + (size_t)chunk * CHUNK) * CV + cv;
  const float4* __restrict__ p = x + base;
  float4*       __restrict__ q = out + base;

  // 1) batch-load chunk into registers (all independent -> full MLP)
  float4 v[CHUNK];
#pragma unroll
  for (int i = 0; i < CHUNK; ++i) v[i] = p[(size_t)i * CV];

  // 2) in-register prefix max (4 independent chains of 15)
#pragma unroll
  for (int i = 1; i < CHUNK; ++i) {
    v[i].x = fmaxf(v[i].x, v[i - 1].x);
    v[i].y = fmaxf(v[i].y, v[i - 1].y);
    v[i].z = fmaxf(v[i].z, v[i - 1].z);
    v[i].w = fmaxf(v[i].w, v[i - 1].w);
  }

  // 3) chunk totals -> LDS -> carry (prefix max of preceding chunk totals)
  totals[chunk][cvl] = v[CHUNK - 1];
  __syncthreads();

  const float ninf = -__builtin_inff();
  float4 carry = make_float4(ninf, ninf, ninf, ninf);
  for (int c = 0; c < chunk; ++c) {  // wave-uniform trip count
    float4 t = totals[c][cvl];
    carry.x = fmaxf(carry.x, t.x);
    carry.y = fmaxf(carry.y, t.y);
    carry.z = fmaxf(carry.z, t.z);
    carry.w = fmaxf(carry.w, t.w);
  }

  // 4) apply carry + store (coalesced 1 KiB per wave-instruction)
#pragma unroll
  for (int i = 0; i < CHUNK; ++i) {
    float4 o;
    o.x = fmaxf(carry.x, v[i].x);
    o.y = fmaxf(carry.y, v[i].y);
    o.z = fmaxf(carry.z, v[i].z);
    o.w = fmaxf(carry.w, v[i].w);
    q[(size_t)i * CV] = o;
  }
}

extern "C" void kernel_launch(void* const* d_in, const int* in_sizes, int n_in,
                              void* d_out, int out_size, void* d_ws, size_t ws_size,
                              hipStream_t stream) {
  const float4* x = (const float4*)d_in[0];
  float4* out = (float4*)d_out;

  // 1024 rows x 2 half-C blocks = 2048 blocks of 512 threads.
  constexpr int ROWS = 8 * 128;
  cummax_scan<<<ROWS * 2, 512, 0, stream>>>(x, out);
}